// Round 3
// baseline (581.788 us; speedup 1.0000x reference)
//
#include <hip/hip_runtime.h>

// MetaUpscale: out[n,o,oy,ox] = sum_{ch<576} patch[n][oy/2][ox/2][ch] * lw[oy][ox][ch][o]
// patch[n][hy][wx][c*9 + kh*3 + kw] = x[n][c][hy+kh-1][wx+kw-1] (zero pad)
// N=2, C=64, H=W=128, S=2 -> out (2,3,256,256). All FP32.
//
// Roofline: lw is a 453 MB single-use stream -> ~72 us @ 6.3 TB/s. Strategy:
// keep lw in registers exactly as coalesced-loaded (7x dwordx4 per wave =
// the minimal 432 cache lines/pixel) and redistribute the SHARED patch
// operand via LDS broadcast. Element g = 256*IT + 4*lane + J of a pixel's lw
// slice is lw[ch = g/3][o = g%3] with o = (IT+lane+J) mod 3; accumulate into
// acc[(IT+J)%3] (compile-time index), un-rotate by lane%3 before reduction.
//
// ch strength-reduction (no per-element divide): with q=lane/3, l3=lane%3,
// c=IT+J (compile-time):  ch = 85*IT + lane + q + c/3 + inc,
//   inc = 0 (c%3==0) | (l3==2) (c%3==1) | (l3>=1) (c%3==2)
// -> 3 precomputed base pointers + compile-time ds_read offsets.
// LDS = 4.6 KB/block -> occupancy capped by wave slots, not LDS.

namespace {

constexpr int N_  = 2;
constexpr int C_  = 64;
constexpr int H_  = 128;
constexpr int W_  = 128;
constexpr int CH9 = C_ * 9;    // 576
constexpr int PIX = CH9 * 3;   // 1728 floats of lw per output pixel
constexpr int OH  = 256;
constexpr int OW  = 256;

__global__ __launch_bounds__(256)
void metaupscale_kernel(const float* __restrict__ x,
                        const float* __restrict__ lw,
                        float* __restrict__ out) {
    __shared__ float2 patch2[CH9];   // 4.6 KB: (n=0, n=1) patch pairs

    const int blk = blockIdx.x;      // 0 .. H*W-1, one input pixel per block
    const int hy  = blk / W_;
    const int wx  = blk - hy * W_;
    const int tid = threadIdx.x;

    // ---- Stage the 3x3xC patch (both batch images as float2) into LDS ----
    for (int e = tid; e < CH9; e += 256) {
        const int c = e / 9;
        const int j = e - c * 9;
        const int h = hy + (j / 3) - 1;
        const int w = wx + (j % 3) - 1;
        float v0 = 0.0f, v1 = 0.0f;
        if ((unsigned)h < (unsigned)H_ && (unsigned)w < (unsigned)W_) {
            const size_t base = ((size_t)c * H_ + h) * W_ + w;
            v0 = x[base];
            v1 = x[(size_t)C_ * H_ * W_ + base];
        }
        patch2[e] = make_float2(v0, v1);
    }
    __syncthreads();

    // ---- Each of the 4 waves handles one output sub-pixel ----
    const int wave = tid >> 6;       // 0..3
    const int lane = tid & 63;
    const int oy   = hy * 2 + (wave >> 1);
    const int ox   = wx * 2 + (wave & 1);
    const int q    = lane / 3;       // one divide per lane, hoisted
    const int l3   = lane - 3 * q;   // lane % 3

    const float4* __restrict__ lwp4 =
        reinterpret_cast<const float4*>(lw + (size_t)(oy * OW + ox) * PIX);

    // ---- Minimal coalesced stream: 432 float4 = 6 full wave-iters + 48-lane tail
    float4 r0 = lwp4[0 * 64 + lane];
    float4 r1 = lwp4[1 * 64 + lane];
    float4 r2 = lwp4[2 * 64 + lane];
    float4 r3 = lwp4[3 * 64 + lane];
    float4 r4 = lwp4[4 * 64 + lane];
    float4 r5 = lwp4[5 * 64 + lane];
    float4 r6 = make_float4(0.0f, 0.0f, 0.0f, 0.0f);
    if (lane < 48) r6 = lwp4[6 * 64 + lane];

    // Three base pointers encode the lane-dependent part of ch:
    const float2* __restrict__ pb0 = patch2 + (lane + q);        // c%3 == 0
    const float2* __restrict__ pb1 = pb0 + (l3 == 2 ? 1 : 0);    // c%3 == 1
    const float2* __restrict__ pb2 = pb0 + (l3 >= 1 ? 1 : 0);    // c%3 == 2

    float acc0[3] = {0.0f, 0.0f, 0.0f};   // n=0, rotated output index r
    float acc1[3] = {0.0f, 0.0f, 0.0f};   // n=1

    // ch = 85*IT + (lane+q) + c/3 + inc(c%3, l3); all IT/J-dependent parts are
    // compile-time -> single ds_read_b64 with immediate offset per element.
#define ACC_ELEM(IT, J, VV) do {                                        \
        const int    C_IJ = (IT) + (J);                                 \
        const float2* pp  = ((C_IJ % 3) == 0) ? pb0                     \
                          : ((C_IJ % 3) == 1) ? pb1 : pb2;              \
        const float2  p   = pp[85 * (IT) + (C_IJ / 3)];                 \
        acc0[C_IJ % 3] += p.x * (VV);                                   \
        acc1[C_IJ % 3] += p.y * (VV);                                   \
    } while (0)

#define ACC_VEC(IT, R) do {                                             \
        ACC_ELEM(IT, 0, (R).x); ACC_ELEM(IT, 1, (R).y);                 \
        ACC_ELEM(IT, 2, (R).z); ACC_ELEM(IT, 3, (R).w);                 \
    } while (0)

    ACC_VEC(0, r0);
    ACC_VEC(1, r1);
    ACC_VEC(2, r2);
    ACC_VEC(3, r3);
    ACC_VEC(4, r4);
    ACC_VEC(5, r5);
    if (lane < 48) ACC_VEC(6, r6);   // guard: keeps ch < 576 (no OOB LDS read)

#undef ACC_VEC
#undef ACC_ELEM

    // ---- Un-rotate: lane's acc[r] belongs to output o = (r + l3) % 3 ----
    float f00, f01, f02, f10, f11, f12;
    if (l3 == 0) {
        f00 = acc0[0]; f01 = acc0[1]; f02 = acc0[2];
        f10 = acc1[0]; f11 = acc1[1]; f12 = acc1[2];
    } else if (l3 == 1) {
        f00 = acc0[2]; f01 = acc0[0]; f02 = acc0[1];
        f10 = acc1[2]; f11 = acc1[0]; f12 = acc1[1];
    } else {
        f00 = acc0[1]; f01 = acc0[2]; f02 = acc0[0];
        f10 = acc1[1]; f11 = acc1[2]; f12 = acc1[0];
    }

    // ---- Reduce the 6 values across the 64-lane wave ----
    #pragma unroll
    for (int off = 32; off > 0; off >>= 1) {
        f00 += __shfl_down(f00, off, 64);
        f01 += __shfl_down(f01, off, 64);
        f02 += __shfl_down(f02, off, 64);
        f10 += __shfl_down(f10, off, 64);
        f11 += __shfl_down(f11, off, 64);
        f12 += __shfl_down(f12, off, 64);
    }

    if (lane == 0) {
        const size_t pix = (size_t)oy * OW + ox;
        out[(0 * 3 + 0) * (size_t)(OH * OW) + pix] = f00;
        out[(0 * 3 + 1) * (size_t)(OH * OW) + pix] = f01;
        out[(0 * 3 + 2) * (size_t)(OH * OW) + pix] = f02;
        out[(1 * 3 + 0) * (size_t)(OH * OW) + pix] = f10;
        out[(1 * 3 + 1) * (size_t)(OH * OW) + pix] = f11;
        out[(1 * 3 + 2) * (size_t)(OH * OW) + pix] = f12;
    }
}

}  // namespace

extern "C" void kernel_launch(void* const* d_in, const int* in_sizes, int n_in,
                              void* d_out, int out_size, void* d_ws, size_t ws_size,
                              hipStream_t stream) {
    const float* x  = (const float*)d_in[0];
    const float* lw = (const float*)d_in[1];
    // d_in[2] = scale (int32, ==2) — compile-time constant here.
    float* out = (float*)d_out;

    const int grid = H_ * W_;   // 16384 blocks, one per input pixel
    metaupscale_kernel<<<grid, 256, 0, stream>>>(x, lw, out);
}